// Round 6
// baseline (6528.849 us; speedup 1.0000x reference)
//
#include <hip/hip_runtime.h>

#define NN 50000
#define FF 24
#define HH 128
#define TT 12
#define EE 800000
#define HORZ 6

// ---------------- mask dtype detection + canonicalization ----------------

__global__ void k_maskdetect(const unsigned char* __restrict__ m, int* __restrict__ flag) {
    int i = blockIdx.x * 256 + threadIdx.x;
    if (i < 16384 && (i & 3) != 0 && m[i] != 0) atomicOr(flag, 1);
}

__global__ void k_maskconv(const unsigned char* __restrict__ mraw, const int* __restrict__ flag,
                           unsigned char* __restrict__ mout) {
    int i = blockIdx.x * 256 + threadIdx.x;
    if (i >= TT * NN) return;
    if (*flag) mout[i] = (mraw[i] != 0);
    else       mout[i] = (((const int*)mraw)[i] != 0);
}

// ---------------- CSR build: histogram -> scan(+cursor) -> fill ----------------

__global__ void k_hist(const int* __restrict__ ei, int* __restrict__ cnt) {
    int idx = blockIdx.x * 256 + threadIdx.x;          // over T*E
    if (idx >= TT * EE) return;
    int t = idx / EE, e = idx - t * EE;
    int dst = ei[((size_t)t * 2 + 1) * EE + e];
    atomicAdd(&cnt[t * NN + dst], 1);
}

__global__ void k_scan(const int* __restrict__ cnt, int* __restrict__ offs,
                       int* __restrict__ cursor) {
    __shared__ int sums[1024];
    int t = blockIdx.x, tid = threadIdx.x;
    const int per = (NN + 1023) / 1024;                // 49
    int base = tid * per;
    int s = 0;
    for (int i = 0; i < per; i++) {
        int idx = base + i;
        if (idx < NN) s += cnt[t * NN + idx];
    }
    sums[tid] = s;
    __syncthreads();
    for (int off = 1; off < 1024; off <<= 1) {
        int tv = (tid >= off) ? sums[tid - off] : 0;
        __syncthreads();
        sums[tid] += tv;
        __syncthreads();
    }
    int run = sums[tid] - s;                           // exclusive prefix
    for (int i = 0; i < per; i++) {
        int idx = base + i;
        if (idx < NN) {
            offs[t * (NN + 1) + idx] = run;
            cursor[t * NN + idx] = run;
            run += cnt[t * NN + idx];
        }
    }
    if (tid == 1023) offs[t * (NN + 1) + NN] = sums[1023];
}

// two independent 4B scatter streams (R4 layout): latency-bound scatter wants MLP.
__global__ void k_fill(const int* __restrict__ ei, const float* __restrict__ ea,
                       int* __restrict__ cursor, int* __restrict__ srcs,
                       float* __restrict__ eav) {
    int idx = blockIdx.x * 256 + threadIdx.x;          // over T*E
    if (idx >= TT * EE) return;
    int t = idx / EE, e = idx - t * EE;
    int dst = ei[((size_t)t * 2 + 1) * EE + e];
    int src = ei[((size_t)t * 2 + 0) * EE + e];
    int pos = atomicAdd(&cursor[t * NN + dst], 1);
    srcs[(size_t)t * EE + pos] = src;
    eav[(size_t)t * EE + pos]  = ea[(size_t)t * EE + e];
}

// deg[n] = sum of incoming ea; dinv = rsqrt(deg+1)
__global__ void k_degdinv(const int* __restrict__ offs, const float* __restrict__ eav,
                          float* __restrict__ dinv) {
    int idx = blockIdx.x * 256 + threadIdx.x;          // over T*N
    if (idx >= TT * NN) return;
    int t = idx / NN, n = idx - t * NN;
    int b = offs[t * (NN + 1) + n], en = offs[t * (NN + 1) + n + 1];
    float s = 0.f;
    for (int j = b; j < en; j++) s += eav[(size_t)t * EE + j];
    dinv[idx] = rsqrtf(s + 1.0f);
}

// edge coefficient: ea *= dinv[src]*dinv[dst]
__global__ void k_coef(const int* __restrict__ offs, const int* __restrict__ srcs,
                       const float* __restrict__ dinv, float* __restrict__ eav) {
    int idx = blockIdx.x * 256 + threadIdx.x;          // over T*N
    if (idx >= TT * NN) return;
    int t = idx / NN, n = idx - t * NN;
    int b = offs[t * (NN + 1) + n], en = offs[t * (NN + 1) + n + 1];
    float di = dinv[idx];
    for (int j = b; j < en; j++) {
        int s = srcs[(size_t)t * EE + j];
        eav[(size_t)t * EE + j] *= di * dinv[t * NN + s];
    }
}

// ---------------- weight folding + transposition ----------------
// CallT[g][c][j] = (Wg @ LWg_top)[j][c]        (3 x HH x FF)
// LWT  [g][c][k] = LWg_bottom[k][c]            (3 x HH x HH)
// headWT[f][cJ]  = headW[cJ][f]                (FF x HH)
// b2[g][c]       = bg @ LWg_top + Lbg

__global__ void k_fold(const float* __restrict__ Wz, const float* __restrict__ Wr,
                       const float* __restrict__ Wh,
                       const float* __restrict__ bz, const float* __restrict__ br,
                       const float* __restrict__ bh,
                       const float* __restrict__ LWz, const float* __restrict__ LWr,
                       const float* __restrict__ LWh,
                       const float* __restrict__ Lbz, const float* __restrict__ Lbr,
                       const float* __restrict__ Lbh,
                       const float* __restrict__ headW,
                       float* __restrict__ CallT, float* __restrict__ b2,
                       float* __restrict__ LWT, float* __restrict__ headWT) {
    int g = blockIdx.x, c = threadIdx.x;               // 3 blocks x 128
    const float* W  = g == 0 ? Wz : (g == 1 ? Wr : Wh);
    const float* LW = g == 0 ? LWz : (g == 1 ? LWr : LWh);
    const float* bg = g == 0 ? bz : (g == 1 ? br : bh);
    const float* Lb = g == 0 ? Lbz : (g == 1 ? Lbr : Lbh);
    for (int j = 0; j < FF; j++) {
        float a = 0.f;
        for (int k = 0; k < HH; k++) a += W[j * HH + k] * LW[k * HH + c];
        CallT[((size_t)g * HH + c) * FF + j] = a;
    }
    float a = Lb[c];
    for (int k = 0; k < HH; k++) a += bg[k] * LW[k * HH + c];
    b2[g * HH + c] = a;
    for (int k = 0; k < HH; k++) {
        LWT[((size_t)g * HH + c) * HH + k] = LW[(HH + k) * HH + c];
    }
    if (g == 0) {
        for (int idx = c; idx < FF * HH; idx += 128) {
            int f = idx / HH, cJ = idx - f * HH;
            headWT[f * HH + cJ] = headW[cJ * FF + f];
        }
    }
}

// ---------------- fused gather + GRU cell (+ head) ----------------

#define FMA8X2(SARR, M0, K, WZ, WR)                                                          \
    {                                                                                        \
        float4 v_;                                                                           \
        v_ = *(const float4*)&SARR[M0 + 0][K];                                               \
        az0 += v_.x*WZ.x + v_.y*WZ.y + v_.z*WZ.z + v_.w*WZ.w;                                \
        ar0 += v_.x*WR.x + v_.y*WR.y + v_.z*WR.z + v_.w*WR.w;                                \
        v_ = *(const float4*)&SARR[M0 + 1][K];                                               \
        az1 += v_.x*WZ.x + v_.y*WZ.y + v_.z*WZ.z + v_.w*WZ.w;                                \
        ar1 += v_.x*WR.x + v_.y*WR.y + v_.z*WR.z + v_.w*WR.w;                                \
        v_ = *(const float4*)&SARR[M0 + 2][K];                                               \
        az2 += v_.x*WZ.x + v_.y*WZ.y + v_.z*WZ.z + v_.w*WZ.w;                                \
        ar2 += v_.x*WR.x + v_.y*WR.y + v_.z*WR.z + v_.w*WR.w;                                \
        v_ = *(const float4*)&SARR[M0 + 3][K];                                               \
        az3 += v_.x*WZ.x + v_.y*WZ.y + v_.z*WZ.z + v_.w*WZ.w;                                \
        ar3 += v_.x*WR.x + v_.y*WR.y + v_.z*WR.z + v_.w*WR.w;                                \
        v_ = *(const float4*)&SARR[M0 + 4][K];                                               \
        az4 += v_.x*WZ.x + v_.y*WZ.y + v_.z*WZ.z + v_.w*WZ.w;                                \
        ar4 += v_.x*WR.x + v_.y*WR.y + v_.z*WR.z + v_.w*WR.w;                                \
        v_ = *(const float4*)&SARR[M0 + 5][K];                                               \
        az5 += v_.x*WZ.x + v_.y*WZ.y + v_.z*WZ.z + v_.w*WZ.w;                                \
        ar5 += v_.x*WR.x + v_.y*WR.y + v_.z*WR.z + v_.w*WR.w;                                \
        v_ = *(const float4*)&SARR[M0 + 6][K];                                               \
        az6 += v_.x*WZ.x + v_.y*WZ.y + v_.z*WZ.z + v_.w*WZ.w;                                \
        ar6 += v_.x*WR.x + v_.y*WR.y + v_.z*WR.z + v_.w*WR.w;                                \
        v_ = *(const float4*)&SARR[M0 + 7][K];                                               \
        az7 += v_.x*WZ.x + v_.y*WZ.y + v_.z*WZ.z + v_.w*WZ.w;                                \
        ar7 += v_.x*WR.x + v_.y*WR.y + v_.z*WR.z + v_.w*WR.w;                                \
    }

#define FMA8X(SARR, M0, K, W4)                                                               \
    {                                                                                        \
        float4 v_;                                                                           \
        v_ = *(const float4*)&SARR[M0 + 0][K]; a0 += v_.x*W4.x + v_.y*W4.y + v_.z*W4.z + v_.w*W4.w; \
        v_ = *(const float4*)&SARR[M0 + 1][K]; a1 += v_.x*W4.x + v_.y*W4.y + v_.z*W4.z + v_.w*W4.w; \
        v_ = *(const float4*)&SARR[M0 + 2][K]; a2 += v_.x*W4.x + v_.y*W4.y + v_.z*W4.z + v_.w*W4.w; \
        v_ = *(const float4*)&SARR[M0 + 3][K]; a3 += v_.x*W4.x + v_.y*W4.y + v_.z*W4.z + v_.w*W4.w; \
        v_ = *(const float4*)&SARR[M0 + 4][K]; a4 += v_.x*W4.x + v_.y*W4.y + v_.z*W4.z + v_.w*W4.w; \
        v_ = *(const float4*)&SARR[M0 + 5][K]; a5 += v_.x*W4.x + v_.y*W4.y + v_.z*W4.z + v_.w*W4.w; \
        v_ = *(const float4*)&SARR[M0 + 6][K]; a6 += v_.x*W4.x + v_.y*W4.y + v_.z*W4.z + v_.w*W4.w; \
        v_ = *(const float4*)&SARR[M0 + 7][K]; a7 += v_.x*W4.x + v_.y*W4.y + v_.z*W4.z + v_.w*W4.w; \
    }

template <int DOHEAD>
__global__ __launch_bounds__(256) void k_cell(
        const float* __restrict__ x, const int* __restrict__ offs,
        const int* __restrict__ srcs, const float* __restrict__ eav,
        const float* __restrict__ dinv,
        const float* __restrict__ hin, const unsigned char* __restrict__ gmask,
        const float* __restrict__ CallT, const float* __restrict__ b2,
        const float* __restrict__ LWT,
        const unsigned char* __restrict__ wmask, float* __restrict__ hout,
        const float* __restrict__ headWT, const float* __restrict__ headb,
        float* __restrict__ y) {
    __shared__ float s_xe[16][FF];
    __shared__ float s_h0[16][HH];
    __shared__ float s_z[16][HH];
    __shared__ float s_hr[16][HH];
    int nb = blockIdx.x * 16;
    int tid = threadIdx.x;

    // ---- phase 0: GCN gather straight into LDS ----
    for (int i = tid; i < 16 * FF; i += 256) {
        int m = i / FF, f = i - m * FF;
        int n = nb + m;
        int b = offs[n], en = offs[n + 1];
        float di = dinv[n];
        float acc = x[(size_t)n * FF + f] * di * di;
        for (int j = b; j < en; j++) {
            acc += x[(size_t)srcs[j] * FF + f] * eav[j];
        }
        s_xe[m][f] = acc;
    }
    for (int i = tid; i < 16 * HH; i += 256) {
        int m = i >> 7, k = i & 127;
        float v = hin[((size_t)nb + m) * HH + k];
        if (gmask && !gmask[nb + m]) v = 0.f;
        s_h0[m][k] = v;
    }
    __syncthreads();

    int g = tid >> 7, c = tid & 127;
    int m0 = g * 8;                                    // row half owned by this thread

    // ---- phase A: z AND r for 8 rows x column c (transposed weights, float4) ----
    {
        const float* CzT  = CallT + (size_t)c * FF;
        const float* CrT  = CallT + (size_t)(HH + c) * FF;
        const float* LWzT = LWT + (size_t)c * HH;
        const float* LWrT = LWT + (size_t)(HH + c) * HH;
        float bbz = b2[c], bbr = b2[HH + c];
        float az0 = bbz, az1 = bbz, az2 = bbz, az3 = bbz, az4 = bbz, az5 = bbz, az6 = bbz, az7 = bbz;
        float ar0 = bbr, ar1 = bbr, ar2 = bbr, ar3 = bbr, ar4 = bbr, ar5 = bbr, ar6 = bbr, ar7 = bbr;
#pragma unroll
        for (int k = 0; k < FF; k += 4) {
            float4 wz = *(const float4*)&CzT[k];
            float4 wr = *(const float4*)&CrT[k];
            FMA8X2(s_xe, m0, k, wz, wr);
        }
#pragma unroll 4
        for (int k = 0; k < HH; k += 4) {
            float4 wz = *(const float4*)&LWzT[k];
            float4 wr = *(const float4*)&LWrT[k];
            FMA8X2(s_h0, m0, k, wz, wr);
        }
#pragma unroll
        for (int r = 0; r < 8; r++) {
            float az = (r == 0) ? az0 : (r == 1) ? az1 : (r == 2) ? az2 : (r == 3) ? az3
                     : (r == 4) ? az4 : (r == 5) ? az5 : (r == 6) ? az6 : az7;
            float ar = (r == 0) ? ar0 : (r == 1) ? ar1 : (r == 2) ? ar2 : (r == 3) ? ar3
                     : (r == 4) ? ar4 : (r == 5) ? ar5 : (r == 6) ? ar6 : ar7;
            s_z[m0 + r][c]  = 1.f / (1.f + __expf(-az));
            s_hr[m0 + r][c] = (1.f / (1.f + __expf(-ar))) * s_h0[m0 + r][c];
        }
    }
    __syncthreads();

    // ---- phase B: htil + GRU update; g=0 rows 0-7, g=1 rows 8-15 ----
    {
        const float* ChT  = CallT + (size_t)(2 * HH + c) * FF;
        const float* LWhT = LWT + (size_t)(2 * HH + c) * HH;
        float bb = b2[2 * HH + c];
        float a0 = bb, a1 = bb, a2 = bb, a3 = bb, a4 = bb, a5 = bb, a6 = bb, a7 = bb;
#pragma unroll
        for (int k = 0; k < FF; k += 4) {
            float4 w4 = *(const float4*)&ChT[k];
            FMA8X(s_xe, m0, k, w4);
        }
#pragma unroll 4
        for (int k = 0; k < HH; k += 4) {
            float4 w4 = *(const float4*)&LWhT[k];
            FMA8X(s_hr, m0, k, w4);
        }
#pragma unroll
        for (int r = 0; r < 8; r++) {
            float a = (r == 0) ? a0 : (r == 1) ? a1 : (r == 2) ? a2 : (r == 3) ? a3
                    : (r == 4) ? a4 : (r == 5) ? a5 : (r == 6) ? a6 : a7;
            int m = m0 + r;
            float e2 = __expf(2.f * a);
            float ht = 1.f - 2.f / (e2 + 1.f);
            float z = s_z[m][c];
            float h0v = s_h0[m][c];
            float hn = z * h0v + (1.f - z) * ht;
            int n = nb + m;
            if (wmask) {
                if (wmask[n]) hout[(size_t)n * HH + c] = hn;
            } else {
                hout[(size_t)n * HH + c] = hn;
            }
            if (DOHEAD) s_z[m][c] = hn;
        }
    }

    if (DOHEAD) {
        __syncthreads();
        for (int i = tid; i < 16 * FF; i += 256) {
            int m = i / FF, f = i - m * FF;
            const float* hw = headWT + (size_t)f * HH;
            float acc = headb[f];
#pragma unroll 8
            for (int cJ = 0; cJ < HH; cJ += 4) {
                float4 hv = *(const float4*)&s_z[m][cJ];
                float4 wv = *(const float4*)&hw[cJ];
                acc += hv.x * wv.x + hv.y * wv.y + hv.z * wv.z + hv.w * wv.w;
            }
            y[(size_t)nb * FF + i] = acc;
        }
    }
}

extern "C" void kernel_launch(void* const* d_in, const int* in_sizes, int n_in,
                              void* d_out, int out_size, void* d_ws, size_t ws_size,
                              hipStream_t stream) {
    const float* x_seq = (const float*)d_in[0];
    const int*   ei    = (const int*)d_in[1];
    const float* ea    = (const float*)d_in[2];
    const unsigned char* mraw = (const unsigned char*)d_in[3];
    const float* Wz  = (const float*)d_in[5];
    const float* Wr  = (const float*)d_in[6];
    const float* Wh  = (const float*)d_in[7];
    const float* bz  = (const float*)d_in[8];
    const float* br  = (const float*)d_in[9];
    const float* bh  = (const float*)d_in[10];
    const float* LWz = (const float*)d_in[11];
    const float* LWr = (const float*)d_in[12];
    const float* LWh = (const float*)d_in[13];
    const float* Lbz = (const float*)d_in[14];
    const float* Lbr = (const float*)d_in[15];
    const float* Lbh = (const float*)d_in[16];
    const float* headW = (const float*)d_in[17];
    const float* headb = (const float*)d_in[18];
    float* out = (float*)d_out;

    char* wp = (char*)d_ws;
    int*   cnt    = (int*)wp;   wp += sizeof(int) * TT * NN;
    int*   cursor = (int*)wp;   wp += sizeof(int) * TT * NN;
    int*   offs   = (int*)wp;   wp += sizeof(int) * TT * (NN + 1);
    int*   srcs   = (int*)wp;   wp += sizeof(int) * (size_t)TT * EE;
    float* eav    = (float*)wp; wp += sizeof(float) * (size_t)TT * EE;
    float* dinv   = (float*)wp; wp += sizeof(float) * TT * NN;
    float* hstore = (float*)wp; wp += sizeof(float) * (size_t)NN * HH;
    float* hp     = (float*)wp; wp += sizeof(float) * (size_t)NN * HH;
    float* CallT  = (float*)wp; wp += sizeof(float) * 3 * HH * FF;
    float* b2     = (float*)wp; wp += sizeof(float) * 3 * HH;
    float* LWT    = (float*)wp; wp += sizeof(float) * 3 * HH * HH;
    float* headWT = (float*)wp; wp += sizeof(float) * FF * HH;
    int*   mflag  = (int*)wp;   wp += 256;
    unsigned char* mask = (unsigned char*)wp; wp += TT * NN;
    if (ws_size < (size_t)(wp - (char*)d_ws)) return;

    hipMemsetAsync(mflag, 0, sizeof(int), stream);
    k_maskdetect<<<64, 256, 0, stream>>>(mraw, mflag);
    k_maskconv<<<(TT * NN + 255) / 256, 256, 0, stream>>>(mraw, mflag, mask);

    // CSR build + norm coefficients (once for all 12 graphs)
    hipMemsetAsync(cnt, 0, sizeof(int) * TT * NN, stream);
    hipMemsetAsync(hstore, 0, sizeof(float) * NN * HH, stream);
    k_hist<<<(TT * EE + 255) / 256, 256, 0, stream>>>(ei, cnt);
    k_scan<<<TT, 1024, 0, stream>>>(cnt, offs, cursor);
    k_fill<<<(TT * EE + 255) / 256, 256, 0, stream>>>(ei, ea, cursor, srcs, eav);
    k_degdinv<<<(TT * NN + 255) / 256, 256, 0, stream>>>(offs, eav, dinv);
    k_coef<<<(TT * NN + 255) / 256, 256, 0, stream>>>(offs, srcs, dinv, eav);
    k_fold<<<3, 128, 0, stream>>>(Wz, Wr, Wh, bz, br, bh, LWz, LWr, LWh, Lbz, Lbr, Lbh,
                                  headW, CallT, b2, LWT, headWT);

    // ---------------- encoder ----------------
    for (int t = 0; t < TT; t++) {
        const float* xt = x_seq + (size_t)t * NN * FF;
        const unsigned char* mt = mask + (size_t)t * NN;
        k_cell<0><<<NN / 16, 256, 0, stream>>>(
            xt, offs + t * (NN + 1), srcs + (size_t)t * EE, eav + (size_t)t * EE,
            dinv + t * NN, hstore, mt, CallT, b2, LWT, mt, hstore,
            nullptr, nullptr, nullptr);
    }

    // ---------------- decoder ----------------
    const int*   offsl = offs + (TT - 1) * (NN + 1);
    const int*   srcsl = srcs + (size_t)(TT - 1) * EE;
    const float* eavl  = eav + (size_t)(TT - 1) * EE;
    const float* dil   = dinv + (TT - 1) * NN;
    for (int k = 0; k < HORZ; k++) {
        const float* xin = (k == 0) ? (x_seq + (size_t)(TT - 1) * NN * FF)
                                    : (out + (size_t)(k - 1) * NN * FF);
        k_cell<1><<<NN / 16, 256, 0, stream>>>(
            xin, offsl, srcsl, eavl, dil,
            (k == 0) ? hstore : hp,
            (k == 0) ? (mask + (size_t)(TT - 1) * NN) : nullptr,
            CallT, b2, LWT, nullptr, hp,
            headWT, headb, out + (size_t)k * NN * FF);
    }
}

// Round 7
// 4471.509 us; speedup vs baseline: 1.4601x; 1.4601x over previous
//
#include <hip/hip_runtime.h>

#define NN 50000
#define FF 24
#define HH 128
#define TT 12
#define EE 800000
#define HORZ 6

// ---------------- mask dtype detection + canonicalization ----------------

__global__ void k_maskdetect(const unsigned char* __restrict__ m, int* __restrict__ flag) {
    int i = blockIdx.x * 256 + threadIdx.x;
    if (i < 16384 && (i & 3) != 0 && m[i] != 0) atomicOr(flag, 1);
}

__global__ void k_maskconv(const unsigned char* __restrict__ mraw, const int* __restrict__ flag,
                           unsigned char* __restrict__ mout) {
    int i = blockIdx.x * 256 + threadIdx.x;
    if (i >= TT * NN) return;
    if (*flag) mout[i] = (mraw[i] != 0);
    else       mout[i] = (((const int*)mraw)[i] != 0);
}

// ---------------- CSR build: histogram(+rank) -> scan -> rank-based fill ----------------

__global__ void k_hist(const int* __restrict__ ei, int* __restrict__ cnt,
                       int* __restrict__ rank) {
    int idx = blockIdx.x * 256 + threadIdx.x;          // over T*E
    if (idx >= TT * EE) return;
    int t = idx / EE, e = idx - t * EE;
    int dst = ei[((size_t)t * 2 + 1) * EE + e];
    rank[idx] = atomicAdd(&cnt[t * NN + dst], 1);      // rank within dst row, coalesced store
}

__global__ void k_scan(const int* __restrict__ cnt, int* __restrict__ offs) {
    __shared__ int sums[1024];
    int t = blockIdx.x, tid = threadIdx.x;
    const int per = (NN + 1023) / 1024;                // 49
    int base = tid * per;
    int s = 0;
    for (int i = 0; i < per; i++) {
        int idx = base + i;
        if (idx < NN) s += cnt[t * NN + idx];
    }
    sums[tid] = s;
    __syncthreads();
    for (int off = 1; off < 1024; off <<= 1) {
        int tv = (tid >= off) ? sums[tid - off] : 0;
        __syncthreads();
        sums[tid] += tv;
        __syncthreads();
    }
    int run = sums[tid] - s;                           // exclusive prefix
    for (int i = 0; i < per; i++) {
        int idx = base + i;
        if (idx < NN) {
            offs[t * (NN + 1) + idx] = run;
            run += cnt[t * NN + idx];
        }
    }
    if (tid == 1023) offs[t * (NN + 1) + NN] = sums[1023];
}

// atomic-free fill: pos = offs[dst] + rank[e]; two independent 4B scatter streams (MLP).
__global__ void k_fill(const int* __restrict__ ei, const float* __restrict__ ea,
                       const int* __restrict__ offs, const int* __restrict__ rank,
                       int* __restrict__ srcs, float* __restrict__ eav) {
    int idx = blockIdx.x * 256 + threadIdx.x;          // over T*E
    if (idx >= TT * EE) return;
    int t = idx / EE, e = idx - t * EE;
    int dst = ei[((size_t)t * 2 + 1) * EE + e];
    int src = ei[((size_t)t * 2 + 0) * EE + e];
    int pos = offs[t * (NN + 1) + dst] + rank[idx];
    srcs[(size_t)t * EE + pos] = src;
    eav[(size_t)t * EE + pos]  = ea[(size_t)t * EE + e];
}

// deg[n] = sum of incoming ea; dinv = rsqrt(deg+1)
__global__ void k_degdinv(const int* __restrict__ offs, const float* __restrict__ eav,
                          float* __restrict__ dinv) {
    int idx = blockIdx.x * 256 + threadIdx.x;          // over T*N
    if (idx >= TT * NN) return;
    int t = idx / NN, n = idx - t * NN;
    int b = offs[t * (NN + 1) + n], en = offs[t * (NN + 1) + n + 1];
    float s = 0.f;
    for (int j = b; j < en; j++) s += eav[(size_t)t * EE + j];
    dinv[idx] = rsqrtf(s + 1.0f);
}

// edge coefficient: ea *= dinv[src]*dinv[dst]
__global__ void k_coef(const int* __restrict__ offs, const int* __restrict__ srcs,
                       const float* __restrict__ dinv, float* __restrict__ eav) {
    int idx = blockIdx.x * 256 + threadIdx.x;          // over T*N
    if (idx >= TT * NN) return;
    int t = idx / NN, n = idx - t * NN;
    int b = offs[t * (NN + 1) + n], en = offs[t * (NN + 1) + n + 1];
    float di = dinv[idx];
    for (int j = b; j < en; j++) {
        int s = srcs[(size_t)t * EE + j];
        eav[(size_t)t * EE + j] *= di * dinv[t * NN + s];
    }
}

// ---------------- weight folding: Cg = Wg @ LWg[0:H], b2g = bg @ LWg[0:H] + Lbg ----------------

__global__ void k_fold(const float* __restrict__ Wz, const float* __restrict__ Wr,
                       const float* __restrict__ Wh,
                       const float* __restrict__ bz, const float* __restrict__ br,
                       const float* __restrict__ bh,
                       const float* __restrict__ LWz, const float* __restrict__ LWr,
                       const float* __restrict__ LWh,
                       const float* __restrict__ Lbz, const float* __restrict__ Lbr,
                       const float* __restrict__ Lbh,
                       float* __restrict__ Call, float* __restrict__ b2) {
    int g = blockIdx.x, c = threadIdx.x;               // 3 blocks x 128
    const float* W  = g == 0 ? Wz : (g == 1 ? Wr : Wh);
    const float* LW = g == 0 ? LWz : (g == 1 ? LWr : LWh);
    const float* bg = g == 0 ? bz : (g == 1 ? br : bh);
    const float* Lb = g == 0 ? Lbz : (g == 1 ? Lbr : Lbh);
    for (int j = 0; j < FF; j++) {
        float a = 0.f;
        for (int k = 0; k < HH; k++) a += W[j * HH + k] * LW[k * HH + c];
        Call[((size_t)g * FF + j) * HH + c] = a;
    }
    float a = Lb[c];
    for (int k = 0; k < HH; k++) a += bg[k] * LW[k * HH + c];
    b2[g * HH + c] = a;
}

// ---------------- gather (float4 over f): xe[n][f4] = x[n][f4]*dinv^2 + sum_e coef*x[src][f4] ----

__global__ void k_gather(const float* __restrict__ x, const int* __restrict__ offs,
                         const int* __restrict__ srcs, const float* __restrict__ eav,
                         const float* __restrict__ dinv, float* __restrict__ xe) {
    int idx = blockIdx.x * 256 + threadIdx.x;          // over N*6 (six float4 per node)
    if (idx >= NN * 6) return;
    int n = idx / 6, q = idx - n * 6;
    int b = offs[n], en = offs[n + 1];
    float di = dinv[n];
    float sc = di * di;
    float4 acc = *(const float4*)&x[(size_t)n * FF + q * 4];
    acc.x *= sc; acc.y *= sc; acc.z *= sc; acc.w *= sc;
    for (int j = b; j < en; j++) {
        int s = srcs[j];
        float w = eav[j];
        float4 v = *(const float4*)&x[(size_t)s * FF + q * 4];
        acc.x += v.x * w; acc.y += v.y * w; acc.z += v.z * w; acc.w += v.w * w;
    }
    *(float4*)&xe[(size_t)n * FF + q * 4] = acc;
}

// ---------------- fused GRU cell (R5 structure: coalesced weight loads, paired z/r) ----------------

#define FMA8X2(SARR, M0, K)                                                                  \
    {                                                                                        \
        float4 v_;                                                                           \
        v_ = *(const float4*)&SARR[M0 + 0][K];                                               \
        az0 += v_.x*wz0 + v_.y*wz1 + v_.z*wz2 + v_.w*wz3;                                    \
        ar0 += v_.x*wr0 + v_.y*wr1 + v_.z*wr2 + v_.w*wr3;                                    \
        v_ = *(const float4*)&SARR[M0 + 1][K];                                               \
        az1 += v_.x*wz0 + v_.y*wz1 + v_.z*wz2 + v_.w*wz3;                                    \
        ar1 += v_.x*wr0 + v_.y*wr1 + v_.z*wr2 + v_.w*wr3;                                    \
        v_ = *(const float4*)&SARR[M0 + 2][K];                                               \
        az2 += v_.x*wz0 + v_.y*wz1 + v_.z*wz2 + v_.w*wz3;                                    \
        ar2 += v_.x*wr0 + v_.y*wr1 + v_.z*wr2 + v_.w*wr3;                                    \
        v_ = *(const float4*)&SARR[M0 + 3][K];                                               \
        az3 += v_.x*wz0 + v_.y*wz1 + v_.z*wz2 + v_.w*wz3;                                    \
        ar3 += v_.x*wr0 + v_.y*wr1 + v_.z*wr2 + v_.w*wr3;                                    \
        v_ = *(const float4*)&SARR[M0 + 4][K];                                               \
        az4 += v_.x*wz0 + v_.y*wz1 + v_.z*wz2 + v_.w*wz3;                                    \
        ar4 += v_.x*wr0 + v_.y*wr1 + v_.z*wr2 + v_.w*wr3;                                    \
        v_ = *(const float4*)&SARR[M0 + 5][K];                                               \
        az5 += v_.x*wz0 + v_.y*wz1 + v_.z*wz2 + v_.w*wz3;                                    \
        ar5 += v_.x*wr0 + v_.y*wr1 + v_.z*wr2 + v_.w*wr3;                                    \
        v_ = *(const float4*)&SARR[M0 + 6][K];                                               \
        az6 += v_.x*wz0 + v_.y*wz1 + v_.z*wz2 + v_.w*wz3;                                    \
        ar6 += v_.x*wr0 + v_.y*wr1 + v_.z*wr2 + v_.w*wr3;                                    \
        v_ = *(const float4*)&SARR[M0 + 7][K];                                               \
        az7 += v_.x*wz0 + v_.y*wz1 + v_.z*wz2 + v_.w*wz3;                                    \
        ar7 += v_.x*wr0 + v_.y*wr1 + v_.z*wr2 + v_.w*wr3;                                    \
    }

#define FMA8X(SARR, M0, K)                                                        \
    {                                                                             \
        float4 v_;                                                                \
        v_ = *(const float4*)&SARR[M0 + 0][K]; a0 += v_.x*w0 + v_.y*w1 + v_.z*w2 + v_.w*w3; \
        v_ = *(const float4*)&SARR[M0 + 1][K]; a1 += v_.x*w0 + v_.y*w1 + v_.z*w2 + v_.w*w3; \
        v_ = *(const float4*)&SARR[M0 + 2][K]; a2 += v_.x*w0 + v_.y*w1 + v_.z*w2 + v_.w*w3; \
        v_ = *(const float4*)&SARR[M0 + 3][K]; a3 += v_.x*w0 + v_.y*w1 + v_.z*w2 + v_.w*w3; \
        v_ = *(const float4*)&SARR[M0 + 4][K]; a4 += v_.x*w0 + v_.y*w1 + v_.z*w2 + v_.w*w3; \
        v_ = *(const float4*)&SARR[M0 + 5][K]; a5 += v_.x*w0 + v_.y*w1 + v_.z*w2 + v_.w*w3; \
        v_ = *(const float4*)&SARR[M0 + 6][K]; a6 += v_.x*w0 + v_.y*w1 + v_.z*w2 + v_.w*w3; \
        v_ = *(const float4*)&SARR[M0 + 7][K]; a7 += v_.x*w0 + v_.y*w1 + v_.z*w2 + v_.w*w3; \
    }

template <int DOHEAD>
__global__ __launch_bounds__(256) void k_cell(
        const float* __restrict__ xe, const float* __restrict__ hin,
        const unsigned char* __restrict__ gmask,
        const float* __restrict__ Call, const float* __restrict__ b2,
        const float* __restrict__ LWz, const float* __restrict__ LWr,
        const float* __restrict__ LWh,
        const unsigned char* __restrict__ wmask, float* __restrict__ hout,
        const float* __restrict__ headW, const float* __restrict__ headb,
        float* __restrict__ y) {
    __shared__ float s_xe[16][FF];
    __shared__ float s_h0[16][HH];
    __shared__ float s_z[16][HH];
    __shared__ float s_hr[16][HH];
    int nb = blockIdx.x * 16;
    int tid = threadIdx.x;

    for (int i = tid; i < 16 * FF; i += 256) {
        s_xe[i / FF][i % FF] = xe[(size_t)nb * FF + i];
    }
    for (int i = tid; i < 16 * HH; i += 256) {
        int m = i >> 7, k = i & 127;
        float v = hin[((size_t)nb + m) * HH + k];
        if (gmask && !gmask[nb + m]) v = 0.f;
        s_h0[m][k] = v;
    }
    __syncthreads();

    int g = tid >> 7, c = tid & 127;
    int m0 = g * 8;                                    // row half owned by this thread

    // ---- phase A: z AND r for 8 rows x column c ----
    {
        const float* Cz   = Call;
        const float* Cr   = Call + (size_t)FF * HH;
        const float* LWzb = LWz + (size_t)HH * HH;
        const float* LWrb = LWr + (size_t)HH * HH;
        float bbz = b2[c], bbr = b2[HH + c];
        float az0 = bbz, az1 = bbz, az2 = bbz, az3 = bbz, az4 = bbz, az5 = bbz, az6 = bbz, az7 = bbz;
        float ar0 = bbr, ar1 = bbr, ar2 = bbr, ar3 = bbr, ar4 = bbr, ar5 = bbr, ar6 = bbr, ar7 = bbr;
#pragma unroll
        for (int k = 0; k < FF; k += 4) {
            float wz0 = Cz[(k + 0) * HH + c], wz1 = Cz[(k + 1) * HH + c];
            float wz2 = Cz[(k + 2) * HH + c], wz3 = Cz[(k + 3) * HH + c];
            float wr0 = Cr[(k + 0) * HH + c], wr1 = Cr[(k + 1) * HH + c];
            float wr2 = Cr[(k + 2) * HH + c], wr3 = Cr[(k + 3) * HH + c];
            FMA8X2(s_xe, m0, k);
        }
#pragma unroll 4
        for (int k = 0; k < HH; k += 4) {
            float wz0 = LWzb[(k + 0) * HH + c], wz1 = LWzb[(k + 1) * HH + c];
            float wz2 = LWzb[(k + 2) * HH + c], wz3 = LWzb[(k + 3) * HH + c];
            float wr0 = LWrb[(k + 0) * HH + c], wr1 = LWrb[(k + 1) * HH + c];
            float wr2 = LWrb[(k + 2) * HH + c], wr3 = LWrb[(k + 3) * HH + c];
            FMA8X2(s_h0, m0, k);
        }
#pragma unroll
        for (int r = 0; r < 8; r++) {
            float az = (r == 0) ? az0 : (r == 1) ? az1 : (r == 2) ? az2 : (r == 3) ? az3
                     : (r == 4) ? az4 : (r == 5) ? az5 : (r == 6) ? az6 : az7;
            float ar = (r == 0) ? ar0 : (r == 1) ? ar1 : (r == 2) ? ar2 : (r == 3) ? ar3
                     : (r == 4) ? ar4 : (r == 5) ? ar5 : (r == 6) ? ar6 : ar7;
            s_z[m0 + r][c]  = 1.f / (1.f + __expf(-az));
            s_hr[m0 + r][c] = (1.f / (1.f + __expf(-ar))) * s_h0[m0 + r][c];
        }
    }
    __syncthreads();

    // ---- phase B: htil + GRU update; g=0 rows 0-7, g=1 rows 8-15 ----
    {
        const float* Ch   = Call + (size_t)2 * FF * HH;
        const float* LWhb = LWh + (size_t)HH * HH;
        float bb = b2[2 * HH + c];
        float a0 = bb, a1 = bb, a2 = bb, a3 = bb, a4 = bb, a5 = bb, a6 = bb, a7 = bb;
#pragma unroll
        for (int k = 0; k < FF; k += 4) {
            float w0 = Ch[(k + 0) * HH + c], w1 = Ch[(k + 1) * HH + c];
            float w2 = Ch[(k + 2) * HH + c], w3 = Ch[(k + 3) * HH + c];
            FMA8X(s_xe, m0, k);
        }
#pragma unroll 4
        for (int k = 0; k < HH; k += 4) {
            float w0 = LWhb[(k + 0) * HH + c], w1 = LWhb[(k + 1) * HH + c];
            float w2 = LWhb[(k + 2) * HH + c], w3 = LWhb[(k + 3) * HH + c];
            FMA8X(s_hr, m0, k);
        }
#pragma unroll
        for (int r = 0; r < 8; r++) {
            float a = (r == 0) ? a0 : (r == 1) ? a1 : (r == 2) ? a2 : (r == 3) ? a3
                    : (r == 4) ? a4 : (r == 5) ? a5 : (r == 6) ? a6 : a7;
            int m = m0 + r;
            float e2 = __expf(2.f * a);
            float ht = 1.f - 2.f / (e2 + 1.f);
            float z = s_z[m][c];
            float h0v = s_h0[m][c];
            float hn = z * h0v + (1.f - z) * ht;
            int n = nb + m;
            if (wmask) {
                if (wmask[n]) hout[(size_t)n * HH + c] = hn;
            } else {
                hout[(size_t)n * HH + c] = hn;
            }
            if (DOHEAD) s_z[m][c] = hn;
        }
    }

    if (DOHEAD) {
        __syncthreads();
        for (int i = tid; i < 16 * FF; i += 256) {
            int m = i / FF, f = i - m * FF;
            float acc = headb[f];
#pragma unroll 8
            for (int cJ = 0; cJ < HH; cJ++) acc += s_z[m][cJ] * headW[cJ * FF + f];
            y[(size_t)nb * FF + i] = acc;
        }
    }
}

extern "C" void kernel_launch(void* const* d_in, const int* in_sizes, int n_in,
                              void* d_out, int out_size, void* d_ws, size_t ws_size,
                              hipStream_t stream) {
    const float* x_seq = (const float*)d_in[0];
    const int*   ei    = (const int*)d_in[1];
    const float* ea    = (const float*)d_in[2];
    const unsigned char* mraw = (const unsigned char*)d_in[3];
    const float* Wz  = (const float*)d_in[5];
    const float* Wr  = (const float*)d_in[6];
    const float* Wh  = (const float*)d_in[7];
    const float* bz  = (const float*)d_in[8];
    const float* br  = (const float*)d_in[9];
    const float* bh  = (const float*)d_in[10];
    const float* LWz = (const float*)d_in[11];
    const float* LWr = (const float*)d_in[12];
    const float* LWh = (const float*)d_in[13];
    const float* Lbz = (const float*)d_in[14];
    const float* Lbr = (const float*)d_in[15];
    const float* Lbh = (const float*)d_in[16];
    const float* headW = (const float*)d_in[17];
    const float* headb = (const float*)d_in[18];
    float* out = (float*)d_out;

    char* wp = (char*)d_ws;
    int*   cnt    = (int*)wp;   wp += sizeof(int) * TT * NN;
    int*   offs   = (int*)wp;   wp += sizeof(int) * TT * (NN + 1);
    int*   rank   = (int*)wp;   wp += sizeof(int) * (size_t)TT * EE;
    int*   srcs   = (int*)wp;   wp += sizeof(int) * (size_t)TT * EE;
    float* eav    = (float*)wp; wp += sizeof(float) * (size_t)TT * EE;
    float* dinv   = (float*)wp; wp += sizeof(float) * TT * NN;
    float* hstore = (float*)wp; wp += sizeof(float) * (size_t)NN * HH;
    float* hp     = (float*)wp; wp += sizeof(float) * (size_t)NN * HH;
    float* xebuf  = (float*)wp; wp += sizeof(float) * NN * FF;
    float* Call   = (float*)wp; wp += sizeof(float) * 3 * FF * HH;
    float* b2     = (float*)wp; wp += sizeof(float) * 3 * HH;
    int*   mflag  = (int*)wp;   wp += 256;
    unsigned char* mask = (unsigned char*)wp; wp += TT * NN;
    if (ws_size < (size_t)(wp - (char*)d_ws)) return;

    hipMemsetAsync(mflag, 0, sizeof(int), stream);
    k_maskdetect<<<64, 256, 0, stream>>>(mraw, mflag);
    k_maskconv<<<(TT * NN + 255) / 256, 256, 0, stream>>>(mraw, mflag, mask);

    // CSR build + norm coefficients (once for all 12 graphs)
    hipMemsetAsync(cnt, 0, sizeof(int) * TT * NN, stream);
    hipMemsetAsync(hstore, 0, sizeof(float) * NN * HH, stream);
    k_hist<<<(TT * EE + 255) / 256, 256, 0, stream>>>(ei, cnt, rank);
    k_scan<<<TT, 1024, 0, stream>>>(cnt, offs);
    k_fill<<<(TT * EE + 255) / 256, 256, 0, stream>>>(ei, ea, offs, rank, srcs, eav);
    k_degdinv<<<(TT * NN + 255) / 256, 256, 0, stream>>>(offs, eav, dinv);
    k_coef<<<(TT * NN + 255) / 256, 256, 0, stream>>>(offs, srcs, dinv, eav);
    k_fold<<<3, 128, 0, stream>>>(Wz, Wr, Wh, bz, br, bh, LWz, LWr, LWh, Lbz, Lbr, Lbh, Call, b2);

    // ---------------- encoder ----------------
    for (int t = 0; t < TT; t++) {
        const float* xt = x_seq + (size_t)t * NN * FF;
        const unsigned char* mt = mask + (size_t)t * NN;
        k_gather<<<(NN * 6 + 255) / 256, 256, 0, stream>>>(
            xt, offs + t * (NN + 1), srcs + (size_t)t * EE, eav + (size_t)t * EE,
            dinv + t * NN, xebuf);
        k_cell<0><<<NN / 16, 256, 0, stream>>>(
            xebuf, hstore, mt, Call, b2, LWz, LWr, LWh, mt, hstore,
            nullptr, nullptr, nullptr);
    }

    // ---------------- decoder ----------------
    const int*   offsl = offs + (TT - 1) * (NN + 1);
    const int*   srcsl = srcs + (size_t)(TT - 1) * EE;
    const float* eavl  = eav + (size_t)(TT - 1) * EE;
    const float* dil   = dinv + (TT - 1) * NN;
    for (int k = 0; k < HORZ; k++) {
        const float* xin = (k == 0) ? (x_seq + (size_t)(TT - 1) * NN * FF)
                                    : (out + (size_t)(k - 1) * NN * FF);
        k_gather<<<(NN * 6 + 255) / 256, 256, 0, stream>>>(
            xin, offsl, srcsl, eavl, dil, xebuf);
        k_cell<1><<<NN / 16, 256, 0, stream>>>(
            xebuf, (k == 0) ? hstore : hp,
            (k == 0) ? (mask + (size_t)(TT - 1) * NN) : nullptr,
            Call, b2, LWz, LWr, LWh, nullptr, hp,
            headW, headb, out + (size_t)k * NN * FF);
    }
}